// Round 1
// baseline (2730.581 us; speedup 1.0000x reference)
//
#include <hip/hip_runtime.h>

// Conv 3x3 SAME, stride 1, C=16 -> O=16, fp32.
// Input viewed as NHWC via raw reshape of NCHW buffer:
//   x[b,h,w,c] = flat[b*16777216 + (h*1024 + w)*16 + c]
// Weight HWIO: w[kh,kw,c,o] = flat[((kh*3+kw)*16 + c)*16 + o]
// Output NCHW: out[b,o,h,w] = flat[((b*16+o)*1024 + h)*1024 + w]

constexpr int Hs = 1024, Ws = 1024, Cs = 16, Os = 16;

__global__ __launch_bounds__(256, 2)
void conv3x3_c16o16(const float* __restrict__ x,
                    const float* __restrict__ wgt,
                    float* __restrict__ out)
{
    __shared__ float lw[3 * 3 * Cs * Os];   // 2304 floats = 9 KB
    const int t = threadIdx.x;
    // stage weights: 2304 = 9 * 256 exactly
    #pragma unroll
    for (int i = 0; i < 9; ++i) lw[t + 256 * i] = wgt[t + 256 * i];
    __syncthreads();

    const int bid = blockIdx.x;          // grid = B*H = 8192
    const int b   = bid >> 10;
    const int h   = bid & 1023;
    const int w0  = t << 2;              // 4 pixels per thread, full row per block

    const float* xb = x + (size_t)b * ((size_t)Hs * Ws * Cs);

    float acc[4][16];
    #pragma unroll
    for (int p = 0; p < 4; ++p)
        #pragma unroll
        for (int o = 0; o < 16; ++o) acc[p][o] = 0.f;

    #pragma unroll 1                      // keep body ~26KB, I-cache safe
    for (int kh = 0; kh < 3; ++kh) {
        const int hh = h - 1 + kh;
        if (hh < 0 || hh >= Hs) continue; // block-uniform branch (zero pad)

        // load 6 input pixels (w0-1 .. w0+4) x 16 channels into registers
        float xr[6][16];
        #pragma unroll
        for (int j = 0; j < 6; ++j) {
            const int ww = w0 - 1 + j;
            const bool v = (ww >= 0) && (ww < Ws);
            const float4* src =
                (const float4*)(xb + ((long)hh * Ws + ww) * Cs);
            #pragma unroll
            for (int q = 0; q < 4; ++q) {
                float4 val = v ? src[q] : make_float4(0.f, 0.f, 0.f, 0.f);
                xr[j][4 * q + 0] = val.x;
                xr[j][4 * q + 1] = val.y;
                xr[j][4 * q + 2] = val.z;
                xr[j][4 * q + 3] = val.w;
            }
        }

        #pragma unroll
        for (int c = 0; c < 16; ++c) {
            #pragma unroll
            for (int kw = 0; kw < 3; ++kw) {
                // 16 output-channel weights, broadcast ds_read_b128 x4
                const float* wp = &lw[((kh * 3 + kw) * Cs + c) * Os];
                float wv[16];
                #pragma unroll
                for (int q = 0; q < 4; ++q) {
                    float4 wq = ((const float4*)wp)[q];
                    wv[4 * q + 0] = wq.x;
                    wv[4 * q + 1] = wq.y;
                    wv[4 * q + 2] = wq.z;
                    wv[4 * q + 3] = wq.w;
                }
                #pragma unroll
                for (int p = 0; p < 4; ++p) {
                    const float xv = xr[p + kw][c];
                    #pragma unroll
                    for (int o = 0; o < 16; ++o)
                        acc[p][o] = fmaf(xv, wv[o], acc[p][o]);
                }
            }
        }
    }

    // store: NCHW, float4 along w per output plane (coalesced)
    float* ob = out + (((size_t)b * Os) * Hs + (size_t)h) * Ws + w0;
    #pragma unroll
    for (int o = 0; o < 16; ++o) {
        float4 st = make_float4(acc[0][o], acc[1][o], acc[2][o], acc[3][o]);
        *(float4*)(ob + (size_t)o * (Hs * Ws)) = st;
    }
}

extern "C" void kernel_launch(void* const* d_in, const int* in_sizes, int n_in,
                              void* d_out, int out_size, void* d_ws, size_t ws_size,
                              hipStream_t stream)
{
    const float* x   = (const float*)d_in[0];
    const float* wgt = (const float*)d_in[1];
    float* out       = (float*)d_out;

    dim3 grid(8 * Hs);   // one block per (b, h) row
    dim3 block(256);
    conv3x3_c16o16<<<grid, block, 0, stream>>>(x, wgt, out);
}